// Round 10
// baseline (234.206 us; speedup 1.0000x reference)
//
#include <hip/hip_runtime.h>
#include <hip/hip_bf16.h>

// Residual_Comb_Conv: B=2048, C_IN=64, C_MID=64, C_OUT=128, R=60, K=13
// R15 (resubmit; R9 bench was a container infra failure, no signal).
// Intra-step chunk pipelining in both gemms. R14's counters proved
// reads+MFMA serialize per wave (port 1536 + MFMA 1242 ~= measured 2862
// cyc/CU-step). Full fragment double-buffering doesn't fit the register
// budget (arch 104 + acc 128 = 232 of 256/wave at 2 waves/SIMD), so:
//  - keep af[0..3] live, read B in chunks of 2 fragments one chunk AHEAD
//    of the 8 MFMAs that consume the previous chunk -> each chunk's port
//    time (~48 cyc/SIMD) hides under the prior MFMA burst (~310 cyc);
//    only chunk-0 latency (~200 cyc) exposed per step. Live frags 12->8.
//  - stage-gl16s issue at step TOP so DMA port work lands in the MFMA window.
//  - setprio removed from the loop (scheduler fence + m190: null/negative
//    for lockstep GEMM).
// Step skeleton otherwise unchanged: counted vmcnt + single barrier.

typedef __attribute__((ext_vector_type(8))) short bf16x8;
typedef __attribute__((ext_vector_type(4))) float f32x4;
typedef __attribute__((ext_vector_type(4))) unsigned short us4;
typedef __attribute__((ext_vector_type(8))) unsigned short us8;

#define EPSV 1e-5f
#define PLANE 131072           // 2048*64 shorts per z plane
#define ZTOT  7864320          // 60*PLANE

__device__ __forceinline__ unsigned short f2bf(float f) {
  unsigned int u = __builtin_bit_cast(unsigned int, f);
  u += 0x7FFFu + ((u >> 16) & 1u);   // round-to-nearest-even
  return (unsigned short)(u >> 16);
}
__device__ __forceinline__ float bf2f(unsigned short s) {
  unsigned int u = ((unsigned int)s) << 16;
  return __builtin_bit_cast(float, u);
}

// async global->LDS, 16B per lane, wave-uniform LDS base + lane*16 linear dest
typedef const __attribute__((address_space(1))) unsigned int gas_u32;
typedef __attribute__((address_space(3))) unsigned int las_u32;
__device__ __forceinline__ void gl16(const void* g, void* l) {
  __builtin_amdgcn_global_load_lds((gas_u32*)g, (las_u32*)l, 16, 0, 0);
}

// ---- prep: weights -> bf16 transposed layouts; last block also folds BN params
// params: [a1|b1|a3|b3|a2|b2p] (6*64) + cc (128) = 512 floats
__global__ void prep_w(const float* __restrict__ W1, const float* __restrict__ W2,
                       const float* __restrict__ W3,
                       const float* __restrict__ g1, const float* __restrict__ be1,
                       const float* __restrict__ mu1, const float* __restrict__ va1,
                       const float* __restrict__ c1,
                       const float* __restrict__ g2, const float* __restrict__ be2,
                       const float* __restrict__ mu2, const float* __restrict__ va2,
                       const float* __restrict__ c2,
                       const float* __restrict__ g3, const float* __restrict__ be3,
                       const float* __restrict__ mu3, const float* __restrict__ va3,
                       const float* __restrict__ c3,
                       unsigned short* __restrict__ W1t,
                       unsigned short* __restrict__ W23t,
                       float* __restrict__ params) {
  int t = blockIdx.x * 256 + threadIdx.x;
  if (t < 4096) {                        // W1: 64*64 (o,c) rows
    int o = t >> 6, c = t & 63;
    const float* src = W1 + (o * 64 + c) * 13;
    unsigned short* dst = W1t + o * 832 + c;
    #pragma unroll
    for (int ks = 0; ks < 13; ks++) dst[ks * 64] = f2bf(src[ks]);
  } else if (t < 20480) {                // W2,W3: 2*128*64 rows
    int idx = t - 4096;
    int half = idx >> 13;                // 0 -> W2, 1 -> W3
    int o = (idx >> 6) & 127, c = idx & 63;
    const float* src = (half ? W3 : W2) + (o * 64 + c) * 13;
    unsigned short* dst = W23t + o * 1664 + half * 13 * 64 + c;
    #pragma unroll
    for (int ks = 0; ks < 13; ks++) dst[ks * 64] = f2bf(src[ks]);
  }
  if (blockIdx.x == 79) {
    int u = threadIdx.x;
    if (u < 64) {
      float a1v = g1[u] * rsqrtf(va1[u] + EPSV);
      params[u]       = a1v;
      params[64 + u]  = be1[u] - mu1[u] * a1v;
      float a3v = g3[u] * rsqrtf(va3[u] + EPSV);
      params[128 + u] = a3v;
      params[192 + u] = be3[u] - mu3[u] * a3v;
      float a2v = g2[u] * rsqrtf(va2[u] + EPSV);
      params[256 + u] = a2v;
      params[320 + u] = be2[u] - mu2[u] * a2v + a2v * c1[u];  // fold conv1 bias
    }
    if (u < 128) params[384 + u] = c2[u] + c3[u];
  }
}

// ---- transpose-in: x[b][c][r] f32 -> z1T/z3T[r][b][c] bf16 with act1/act3
__global__ __launch_bounds__(256) void t_in(const float* __restrict__ x,
                                            const float* __restrict__ params,
                                            unsigned short* __restrict__ z1T,
                                            unsigned short* __restrict__ z3T) {
  __shared__ float xt[64 * 61];
  __shared__ float prm[256];
  const int b = blockIdx.x, t = threadIdx.x;
  prm[t] = params[t];                       // a1|b1|a3|b3
  for (int i = t; i < 3840; i += 256) {
    int c = i / 60;
    xt[c * 61 + (i - c * 60)] = x[b * 3840 + i];
  }
  __syncthreads();
  if (t < 240) {
    int r = t >> 2, g = t & 3, c0 = g << 4;
    us8 z1v0, z1v1, z3v0, z3v1;
    #pragma unroll
    for (int j = 0; j < 8; j++) {
      int c = c0 + j;
      float v = xt[c * 61 + r];
      z1v0[j] = f2bf(fmaxf(fmaf(v, prm[c], prm[64 + c]), 0.f));
      z3v0[j] = f2bf(fmaxf(fmaf(v, prm[128 + c], prm[192 + c]), 0.f));
    }
    #pragma unroll
    for (int j = 0; j < 8; j++) {
      int c = c0 + 8 + j;
      float v = xt[c * 61 + r];
      z1v1[j] = f2bf(fmaxf(fmaf(v, prm[c], prm[64 + c]), 0.f));
      z3v1[j] = f2bf(fmaxf(fmaf(v, prm[128 + c], prm[192 + c]), 0.f));
    }
    int idx = (r * 2048 + b) * 64 + c0;
    *(us8*)(z1T + idx) = z1v0;  *(us8*)(z1T + idx + 8) = z1v1;
    *(us8*)(z3T + idx) = z3v0;  *(us8*)(z3T + idx + 8) = z3v1;
  }
}

#define MFMA __builtin_amdgcn_mfma_f32_16x16x32_bf16

// ---- gemm1: block = (r, btile=256 b): C[64 x 256] = W1t[64x832] . z1T-panels.
//      4 waves, each owns cols wv*64..wv*64+63 (4m x 4n); A fragments shared.
//      BK=32, 26 steps, triple-buffered 60 KB. Chunk-pipelined step (R15).
__global__ __launch_bounds__(256, 2) void gemm1(const unsigned short* __restrict__ W1t,
                                                const unsigned short* __restrict__ z1T,
                                                const int* __restrict__ nei,
                                                const float* __restrict__ params,
                                                unsigned short* __restrict__ z2T) {
  __shared__ unsigned short As[3][2048];     // 64 rows x 32 shorts per buf (4 KB)
  __shared__ unsigned short Bs[3][8192];     // 256 rows x 32 shorts per buf (16 KB)
  __shared__ int sOff[13];                   // per-plane byte offsets into z1T

  const int bid = blockIdx.x;
  const int r = bid >> 3, btile = bid & 7;   // bid%8 = btile -> one btile per XCD
  const int b0 = btile << 8;
  const int t = threadIdx.x, wv = t >> 6, lane = t & 63;
  const int quad = lane >> 4, nl = lane & 15;

  if (t < 13) sOff[t] = nei[r * 13 + t] * (PLANE * 2);

  // staging: slab = 16 rows x 64 B = one gl16 per wave.
  const int lr = lane >> 2, lj = lane & 3;
  const int sj = ((lj ^ ((lr >> 1) & 3)) << 4);
  const int aoff = (16 * wv + lr) * 1664 + sj;     // W1t row stride 832 shorts
  int boff[4];
  #pragma unroll
  for (int i = 0; i < 4; i++) boff[i] = (b0 + 16 * (4 * wv + i) + lr) * 128 + sj;

  const char* gAb = (const char*)W1t;
  const char* z1b = (const char*)z1T;

  __syncthreads();                           // sOff visible

  // prologue: stage kn=0 -> buf0, kn=1 -> buf1 (plane 0, halves 0/1)
  {
    const char* gb = z1b + sOff[0];
    gl16(gAb + aoff, &As[0][wv * 512]);
    #pragma unroll
    for (int i = 0; i < 4; i++) gl16(gb + boff[i], &Bs[0][(4 * wv + i) * 512]);
    gl16(gAb + 64 + aoff, &As[1][wv * 512]);
    #pragma unroll
    for (int i = 0; i < 4; i++) gl16(gb + 64 + boff[i], &Bs[1][(4 * wv + i) * 512]);
  }
  asm volatile("s_waitcnt vmcnt(5)" ::: "memory");   // own stage-0 landed
  __builtin_amdgcn_s_barrier();

  const int rc = ((quad ^ ((nl >> 1) & 3)) << 3);    // read-side swizzled chunk
  const int aro = nl * 32 + rc;
  const int bro = (wv * 64 + nl) * 32 + rc;

  f32x4 acc[4][4] = {};
  int cb = 0, sb = 2;
  #pragma unroll 1
  for (int s = 0; s < 25; s++) {
    // stage(s+2) first: DMA port work lands during the MFMA window
    {
      const int kn = s + 2;
      int pn = kn >> 1; if (pn > 12) pn = 12;    // clamp keeps vmcnt uniform
      int off = sOff[pn] + ((kn & 1) << 6);
      const char* ga = gAb + kn * 64;
      const char* gb = z1b + off;
      gl16(ga + aoff, &As[sb][wv * 512]);
      #pragma unroll
      for (int i = 0; i < 4; i++) gl16(gb + boff[i], &Bs[sb][(4 * wv + i) * 512]);
    }
    // chunk-pipelined reads + MFMAs
    const unsigned short* Ab = &As[cb][aro];
    const unsigned short* Bb = &Bs[cb][bro];
    bf16x8 af[4], bfr[4];
    #pragma unroll
    for (int mt = 0; mt < 4; mt++)
      af[mt] = *(const bf16x8*)(Ab + mt * 512);
    bfr[0] = *(const bf16x8*)(Bb + 0);
    bfr[1] = *(const bf16x8*)(Bb + 512);
    #pragma unroll
    for (int j = 0; j < 2; j++) {
      if (j < 1) {
        bfr[2] = *(const bf16x8*)(Bb + 1024);
        bfr[3] = *(const bf16x8*)(Bb + 1536);
      }
      #pragma unroll
      for (int mt = 0; mt < 4; mt++) {
        acc[mt][2 * j]     = MFMA(af[mt], bfr[2 * j],     acc[mt][2 * j],     0, 0, 0);
        acc[mt][2 * j + 1] = MFMA(af[mt], bfr[2 * j + 1], acc[mt][2 * j + 1], 0, 0, 0);
      }
    }
    asm volatile("s_waitcnt vmcnt(5)" ::: "memory");   // stage(s+1) landed (own)
    __builtin_amdgcn_s_barrier();                      // orders buffer reuse
    cb = (cb == 2) ? 0 : cb + 1;
    sb = (sb == 2) ? 0 : sb + 1;
  }
  // peeled last step (s=25, cb=1): Bst(25) certified at s=24's vmcnt/b2
  {
    const unsigned short* Ab = &As[1][aro];
    const unsigned short* Bb = &Bs[1][bro];
    bf16x8 af[4], bfr[4];
    #pragma unroll
    for (int mt = 0; mt < 4; mt++)
      af[mt] = *(const bf16x8*)(Ab + mt * 512);
    #pragma unroll
    for (int nt = 0; nt < 4; nt++)
      bfr[nt] = *(const bf16x8*)(Bb + nt * 512);
    #pragma unroll
    for (int mt = 0; mt < 4; mt++)
      #pragma unroll
      for (int nt = 0; nt < 4; nt++)
        acc[mt][nt] = MFMA(af[mt], bfr[nt], acc[mt][nt], 0, 0, 0);
  }

  // epilogue: act2 -> z2T[r][b][o]
  #pragma unroll
  for (int mt = 0; mt < 4; mt++) {
    int ob = mt * 16 + quad * 4;
    f32x4 av = *(const f32x4*)(params + 256 + ob);
    f32x4 bv = *(const f32x4*)(params + 320 + ob);
    #pragma unroll
    for (int nt = 0; nt < 4; nt++) {
      int col = b0 + wv * 64 + nt * 16 + nl;
      f32x4 a = acc[mt][nt];
      us4 w;
      w.x = f2bf(fmaxf(fmaf(a[0], av[0], bv[0]), 0.f));
      w.y = f2bf(fmaxf(fmaf(a[1], av[1], bv[1]), 0.f));
      w.z = f2bf(fmaxf(fmaf(a[2], av[2], bv[2]), 0.f));
      w.w = f2bf(fmaxf(fmaf(a[3], av[3], bv[3]), 0.f));
      *(us4*)(z2T + (r * 2048 + col) * 64 + ob) = w;
    }
  }
}

// ---- gemm2: block = (btile=256 batches, r): C[128 x 256], 4 waves (2mh x 2nh),
//      wave tile 64 x 128 = 4m x 8n. BK=32, 52 K-steps, triple-buffered 74 KB.
//      Chunk-pipelined step (R15): B read in 4 chunks of 2 frags, one chunk
//      ahead of the 8 MFMAs consuming the previous chunk.
__global__ __launch_bounds__(256, 2) void gemm2(const unsigned short* __restrict__ W23t,
                                                const unsigned short* __restrict__ z2T,
                                                const unsigned short* __restrict__ z3T,
                                                const int* __restrict__ nei,
                                                const float* __restrict__ params,
                                                unsigned short* __restrict__ outT) {
  __shared__ unsigned short As[3][4096];     // 128 rows x 32 shorts per buf (8 KB)
  __shared__ unsigned short Bs[3][8192];     // 256 rows x 32 shorts per buf (16 KB)
  __shared__ int sOff[26];                   // per-plane byte offsets from z2T

  const int bid = blockIdx.x;
  const int r = bid >> 3, btile = bid & 7;   // bid%8 = btile -> one btile per XCD
  const int b0 = btile << 8;
  const int t = threadIdx.x, wv = t >> 6, lane = t & 63;
  const int quad = lane >> 4, nl = lane & 15;
  const int mh = wv >> 1, nh = wv & 1;

  if (t < 26) {
    int idx = t < 13 ? t : t - 13;
    int p = nei[r * 13 + idx];
    sOff[t] = p * (PLANE * 2) + (t < 13 ? 0 : ZTOT * 2);
  }

  // staging geometry: slab = 16 rows x 64 B = 1 KB = one gl16 per wave.
  const int lr = lane >> 2, lj = lane & 3;
  const int sj = ((lj ^ ((lr >> 1) & 3)) << 4);   // byte offset in source row
  int aoff[2];
  #pragma unroll
  for (int i = 0; i < 2; i++) aoff[i] = (16 * (2 * wv + i) + lr) * 3328 + sj;
  int boff[4];
  #pragma unroll
  for (int i = 0; i < 4; i++) boff[i] = (b0 + 16 * (4 * wv + i) + lr) * 128 + sj;

  const char* gAb = (const char*)W23t;
  const char* z2b = (const char*)z2T;

  __syncthreads();                           // sOff visible

  // prologue: stage kn=0 -> buf0, kn=1 -> buf1 (plane 0, halves 0/1)
  {
    const char* gb = z2b + sOff[0];
    #pragma unroll
    for (int i = 0; i < 2; i++) gl16(gAb + aoff[i], &As[0][(2 * wv + i) * 512]);
    #pragma unroll
    for (int i = 0; i < 4; i++) gl16(gb + boff[i], &Bs[0][(4 * wv + i) * 512]);
    #pragma unroll
    for (int i = 0; i < 2; i++) gl16(gAb + 64 + aoff[i], &As[1][(2 * wv + i) * 512]);
    #pragma unroll
    for (int i = 0; i < 4; i++) gl16(gb + 64 + boff[i], &Bs[1][(4 * wv + i) * 512]);
  }
  asm volatile("s_waitcnt vmcnt(6)" ::: "memory");   // own stage-0 landed
  __builtin_amdgcn_s_barrier();                      // everyone's stage-0 landed

  const int rc = ((quad ^ ((nl >> 1) & 3)) << 3);  // read-side swizzled chunk (shorts)
  const int aro = (mh * 64 + nl) * 32 + rc;
  const int bro = (nh * 128 + nl) * 32 + rc;

  f32x4 acc[4][8] = {};
  int cb = 0, sb = 2;                        // compute buf = s%3, stage buf = (s+2)%3
  #pragma unroll 1
  for (int s = 0; s < 51; s++) {
    // stage(s+2) first: DMA port work lands during the MFMA window
    {
      const int kn = s + 2;
      int pn = kn >> 1; if (pn > 25) pn = 25;    // clamp keeps vmcnt uniform
      int off = sOff[pn] + ((kn & 1) << 6);
      const char* ga = gAb + kn * 64;
      const char* gb = z2b + off;
      #pragma unroll
      for (int i = 0; i < 2; i++) gl16(ga + aoff[i], &As[sb][(2 * wv + i) * 512]);
      #pragma unroll
      for (int i = 0; i < 4; i++) gl16(gb + boff[i], &Bs[sb][(4 * wv + i) * 512]);
    }
    // chunk-pipelined reads + MFMAs: B chunk j+1 loads during MFMAs on chunk j
    const unsigned short* Ab = &As[cb][aro];
    const unsigned short* Bb = &Bs[cb][bro];
    bf16x8 af[4], bfr[8];
    #pragma unroll
    for (int mt = 0; mt < 4; mt++)
      af[mt] = *(const bf16x8*)(Ab + mt * 512);
    bfr[0] = *(const bf16x8*)(Bb + 0);
    bfr[1] = *(const bf16x8*)(Bb + 512);
    #pragma unroll
    for (int j = 0; j < 4; j++) {
      if (j < 3) {
        bfr[2 * j + 2] = *(const bf16x8*)(Bb + (2 * j + 2) * 512);
        bfr[2 * j + 3] = *(const bf16x8*)(Bb + (2 * j + 3) * 512);
      }
      #pragma unroll
      for (int mt = 0; mt < 4; mt++) {
        acc[mt][2 * j]     = MFMA(af[mt], bfr[2 * j],     acc[mt][2 * j],     0, 0, 0);
        acc[mt][2 * j + 1] = MFMA(af[mt], bfr[2 * j + 1], acc[mt][2 * j + 1], 0, 0, 0);
      }
    }
    asm volatile("s_waitcnt vmcnt(6)" ::: "memory");   // stage(s+1) landed (own)
    __builtin_amdgcn_s_barrier();                      // orders buffer reuse
    cb = (cb == 2) ? 0 : cb + 1;
    sb = (sb == 2) ? 0 : sb + 1;
  }
  // peeled last step (s=51, cb=0): stage(51) certified at s=50's vmcnt/b2
  {
    const unsigned short* Ab = &As[0][aro];
    const unsigned short* Bb = &Bs[0][bro];
    bf16x8 af[4], bfr[8];
    #pragma unroll
    for (int mt = 0; mt < 4; mt++)
      af[mt] = *(const bf16x8*)(Ab + mt * 512);
    #pragma unroll
    for (int nt = 0; nt < 8; nt++)
      bfr[nt] = *(const bf16x8*)(Bb + nt * 512);
    #pragma unroll
    for (int mt = 0; mt < 4; mt++)
      #pragma unroll
      for (int nt = 0; nt < 8; nt++)
        acc[mt][nt] = MFMA(af[mt], bfr[nt], acc[mt][nt], 0, 0, 0);
  }

  // epilogue: + cc -> outT[r][b][o] bf16
  #pragma unroll
  for (int mt = 0; mt < 4; mt++) {
    int ob = mh * 64 + mt * 16 + quad * 4;
    f32x4 cv = *(const f32x4*)(params + 384 + ob);
    #pragma unroll
    for (int nt = 0; nt < 8; nt++) {
      int col = b0 + nh * 128 + nt * 16 + nl;
      f32x4 a = acc[mt][nt];
      us4 w;
      w.x = f2bf(a[0] + cv[0]);
      w.y = f2bf(a[1] + cv[1]);
      w.z = f2bf(a[2] + cv[2]);
      w.w = f2bf(a[3] + cv[3]);
      *(us4*)(outT + (r * 2048 + col) * 128 + ob) = w;
    }
  }
}

// ---- transpose-out: outT[r][b][o] bf16 -> out[b][o][r] f32
__global__ __launch_bounds__(256) void t_out(const unsigned short* __restrict__ outT,
                                             float* __restrict__ out) {
  __shared__ float ot[60 * 129];
  const int b = blockIdx.x, t = threadIdx.x;
  for (int i = t; i < 1920; i += 256) {
    int r = i >> 5, og = (i & 31) << 2;
    us4 v = *(const us4*)(outT + (r * 2048 + b) * 128 + og);
    ot[r * 129 + og + 0] = bf2f(v.x);
    ot[r * 129 + og + 1] = bf2f(v.y);
    ot[r * 129 + og + 2] = bf2f(v.z);
    ot[r * 129 + og + 3] = bf2f(v.w);
  }
  __syncthreads();
  float* dst = out + b * 7680;
  for (int i = t; i < 7680; i += 256) {
    int o = i / 60, r = i - o * 60;
    dst[i] = ot[r * 129 + o];
  }
}

extern "C" void kernel_launch(void* const* d_in, const int* in_sizes, int n_in,
                              void* d_out, int out_size, void* d_ws, size_t ws_size,
                              hipStream_t stream) {
  const float* x   = (const float*)d_in[0];
  const int*   nei = (const int*)d_in[1];
  const float* g1  = (const float*)d_in[2];
  const float* be1 = (const float*)d_in[3];
  const float* mu1 = (const float*)d_in[4];
  const float* va1 = (const float*)d_in[5];
  const float* W1  = (const float*)d_in[6];
  const float* c1  = (const float*)d_in[7];
  const float* g2  = (const float*)d_in[8];
  const float* be2 = (const float*)d_in[9];
  const float* mu2 = (const float*)d_in[10];
  const float* va2 = (const float*)d_in[11];
  const float* W2  = (const float*)d_in[12];
  const float* c2  = (const float*)d_in[13];
  const float* g3  = (const float*)d_in[14];
  const float* be3 = (const float*)d_in[15];
  const float* mu3 = (const float*)d_in[16];
  const float* va3 = (const float*)d_in[17];
  const float* W3  = (const float*)d_in[18];
  const float* c3  = (const float*)d_in[19];

  // ws layout (63.5 MB): W1t | W23t | params | z2T | z3T | big(z1T ∪ outT)
  unsigned short* W1t  = (unsigned short*)d_ws;
  unsigned short* W23t = W1t + 53248;
  float*          prm  = (float*)(W23t + 212992);
  unsigned short* z2T  = (unsigned short*)(prm + 512);
  unsigned short* z3T  = z2T + ZTOT;
  unsigned short* big  = z3T + ZTOT;       // z1T (read in gemm1) aliases outT (written in gemm2)
  unsigned short* z1T  = big;
  unsigned short* outT = big;

  prep_w<<<80, 256, 0, stream>>>(W1, W2, W3,
                                 g1, be1, mu1, va1, c1,
                                 g2, be2, mu2, va2, c2,
                                 g3, be3, mu3, va3, c3,
                                 W1t, W23t, prm);
  t_in<<<2048, 256, 0, stream>>>(x, prm, z1T, z3T);
  gemm1<<<480, 256, 0, stream>>>(W1t, z1T, nei, prm, z2T);
  gemm2<<<480, 256, 0, stream>>>(W23t, z2T, z3T, nei, prm, outT);
  t_out<<<2048, 256, 0, stream>>>(outT, (float*)d_out);
}

// Round 11
// 219.969 us; speedup vs baseline: 1.0647x; 1.0647x over previous
//
#include <hip/hip_runtime.h>
#include <hip/hip_bf16.h>

// Residual_Comb_Conv: B=2048, C_IN=64, C_MID=64, C_OUT=128, R=60, K=13
// R16: gemms reverted to R14 (best known: gemm2 62 us; R15's chunk-pipeline
// exposed ds_read latency 4x/step -> 74.5 us, reverted). This round attacks
// the stable ~160 us non-gemm2 pool (vs ~80 us bottom-up floor):
//  - prep_w MERGED into t_in: blocks 0-79 also do the W transposes; every
//    block computes act1/act3 BN params locally (2 KB reads + 128 rsqrtf);
//    block 0 writes params[256..511] (the only range gemms read).
//    Removes one launch + one inter-kernel drain gap.
//  - t_out phase 2 vectorized to float4 stores (60 % 4 == 0 so 4 consecutive
//    i never cross an o boundary).
// Delta-total is the gap diagnostic: >=8 us -> fuse more boundaries next;
// <=4 us -> slack is inside t_in/gemm1/t_out.

typedef __attribute__((ext_vector_type(8))) short bf16x8;
typedef __attribute__((ext_vector_type(4))) float f32x4;
typedef __attribute__((ext_vector_type(4))) unsigned short us4;
typedef __attribute__((ext_vector_type(8))) unsigned short us8;

#define EPSV 1e-5f
#define PLANE 131072           // 2048*64 shorts per z plane
#define ZTOT  7864320          // 60*PLANE

__device__ __forceinline__ unsigned short f2bf(float f) {
  unsigned int u = __builtin_bit_cast(unsigned int, f);
  u += 0x7FFFu + ((u >> 16) & 1u);   // round-to-nearest-even
  return (unsigned short)(u >> 16);
}
__device__ __forceinline__ float bf2f(unsigned short s) {
  unsigned int u = ((unsigned int)s) << 16;
  return __builtin_bit_cast(float, u);
}

// async global->LDS, 16B per lane, wave-uniform LDS base + lane*16 linear dest
typedef const __attribute__((address_space(1))) unsigned int gas_u32;
typedef __attribute__((address_space(3))) unsigned int las_u32;
__device__ __forceinline__ void gl16(const void* g, void* l) {
  __builtin_amdgcn_global_load_lds((gas_u32*)g, (las_u32*)l, 16, 0, 0);
}

// ---- t_in (merged with prep): x[b][c][r] f32 -> z1T/z3T[r][b][c] bf16 with
//      act1/act3; blocks 0-79 also transpose W1/W2/W3 -> bf16 K-major; block 0
//      writes params[256..511] = [a2|b2p|cc] (the only range the gemms read).
__global__ __launch_bounds__(256) void t_in(const float* __restrict__ x,
                                            const float* __restrict__ W1,
                                            const float* __restrict__ W2,
                                            const float* __restrict__ W3,
                                            const float* __restrict__ g1, const float* __restrict__ be1,
                                            const float* __restrict__ mu1, const float* __restrict__ va1,
                                            const float* __restrict__ c1,
                                            const float* __restrict__ g2, const float* __restrict__ be2,
                                            const float* __restrict__ mu2, const float* __restrict__ va2,
                                            const float* __restrict__ c2,
                                            const float* __restrict__ g3, const float* __restrict__ be3,
                                            const float* __restrict__ mu3, const float* __restrict__ va3,
                                            const float* __restrict__ c3,
                                            unsigned short* __restrict__ W1t,
                                            unsigned short* __restrict__ W23t,
                                            float* __restrict__ params,
                                            unsigned short* __restrict__ z1T,
                                            unsigned short* __restrict__ z3T) {
  __shared__ float xt[64 * 61];
  __shared__ float prm[256];
  const int b = blockIdx.x, t = threadIdx.x;

  // local act1/act3 params: prm = [a1|b1|a3|b3]
  {
    int u = t & 63;
    float v;
    if (t < 64)       v = g1[u] * rsqrtf(va1[u] + EPSV);
    else if (t < 128) v = be1[u] - mu1[u] * (g1[u] * rsqrtf(va1[u] + EPSV));
    else if (t < 192) v = g3[u] * rsqrtf(va3[u] + EPSV);
    else              v = be3[u] - mu3[u] * (g3[u] * rsqrtf(va3[u] + EPSV));
    prm[t] = v;
  }

  // grafted prep duties (blocks 0-79)
  if (b < 80) {
    int tg = b * 256 + t;
    if (tg < 4096) {                       // W1: 64*64 (o,c) rows
      int o = tg >> 6, c = tg & 63;
      const float* src = W1 + (o * 64 + c) * 13;
      unsigned short* dst = W1t + o * 832 + c;
      #pragma unroll
      for (int ks = 0; ks < 13; ks++) dst[ks * 64] = f2bf(src[ks]);
    } else if (tg < 20480) {               // W2,W3: 2*128*64 rows
      int idx = tg - 4096;
      int half = idx >> 13;                // 0 -> W2, 1 -> W3
      int o = (idx >> 6) & 127, c = idx & 63;
      const float* src = (half ? W3 : W2) + (o * 64 + c) * 13;
      unsigned short* dst = W23t + o * 1664 + half * 13 * 64 + c;
      #pragma unroll
      for (int ks = 0; ks < 13; ks++) dst[ks * 64] = f2bf(src[ks]);
    }
    if (b == 0) {
      int u = t;
      if (u < 64) {
        float a2v = g2[u] * rsqrtf(va2[u] + EPSV);
        params[256 + u] = a2v;
        params[320 + u] = be2[u] - mu2[u] * a2v + a2v * c1[u];   // fold conv1 bias
      }
      if (u < 128) params[384 + u] = c2[u] + c3[u];
    }
  }

  for (int i = t; i < 3840; i += 256) {
    int c = i / 60;
    xt[c * 61 + (i - c * 60)] = x[b * 3840 + i];
  }
  __syncthreads();
  if (t < 240) {
    int r = t >> 2, g = t & 3, c0 = g << 4;
    us8 z1v0, z1v1, z3v0, z3v1;
    #pragma unroll
    for (int j = 0; j < 8; j++) {
      int c = c0 + j;
      float v = xt[c * 61 + r];
      z1v0[j] = f2bf(fmaxf(fmaf(v, prm[c], prm[64 + c]), 0.f));
      z3v0[j] = f2bf(fmaxf(fmaf(v, prm[128 + c], prm[192 + c]), 0.f));
    }
    #pragma unroll
    for (int j = 0; j < 8; j++) {
      int c = c0 + 8 + j;
      float v = xt[c * 61 + r];
      z1v1[j] = f2bf(fmaxf(fmaf(v, prm[c], prm[64 + c]), 0.f));
      z3v1[j] = f2bf(fmaxf(fmaf(v, prm[128 + c], prm[192 + c]), 0.f));
    }
    int idx = (r * 2048 + b) * 64 + c0;
    *(us8*)(z1T + idx) = z1v0;  *(us8*)(z1T + idx + 8) = z1v1;
    *(us8*)(z3T + idx) = z3v0;  *(us8*)(z3T + idx + 8) = z3v1;
  }
}

#define MFMA __builtin_amdgcn_mfma_f32_16x16x32_bf16

// ---- gemm1 (R14): block = (r, btile=256 b): C[64 x 256] = W1t . z1T-panels.
//      4 waves, each owns cols wv*64..wv*64+63 (4m x 4n); A fragments shared.
//      BK=32, 26 steps, triple-buffered 60 KB. Single-barrier step, compiler-
//      interleaved reads/MFMAs, counted vmcnt(5).
__global__ __launch_bounds__(256, 2) void gemm1(const unsigned short* __restrict__ W1t,
                                                const unsigned short* __restrict__ z1T,
                                                const int* __restrict__ nei,
                                                const float* __restrict__ params,
                                                unsigned short* __restrict__ z2T) {
  __shared__ unsigned short As[3][2048];     // 64 rows x 32 shorts per buf (4 KB)
  __shared__ unsigned short Bs[3][8192];     // 256 rows x 32 shorts per buf (16 KB)
  __shared__ int sOff[13];                   // per-plane byte offsets into z1T

  const int bid = blockIdx.x;
  const int r = bid >> 3, btile = bid & 7;   // bid%8 = btile -> one btile per XCD
  const int b0 = btile << 8;
  const int t = threadIdx.x, wv = t >> 6, lane = t & 63;
  const int quad = lane >> 4, nl = lane & 15;

  if (t < 13) sOff[t] = nei[r * 13 + t] * (PLANE * 2);

  // staging: slab = 16 rows x 64 B = one gl16 per wave.
  const int lr = lane >> 2, lj = lane & 3;
  const int sj = ((lj ^ ((lr >> 1) & 3)) << 4);
  const int aoff = (16 * wv + lr) * 1664 + sj;     // W1t row stride 832 shorts
  int boff[4];
  #pragma unroll
  for (int i = 0; i < 4; i++) boff[i] = (b0 + 16 * (4 * wv + i) + lr) * 128 + sj;

  const char* gAb = (const char*)W1t;
  const char* z1b = (const char*)z1T;

  __syncthreads();                           // sOff visible

  // prologue: stage kn=0 -> buf0, kn=1 -> buf1 (plane 0, halves 0/1)
  {
    const char* gb = z1b + sOff[0];
    gl16(gAb + aoff, &As[0][wv * 512]);
    #pragma unroll
    for (int i = 0; i < 4; i++) gl16(gb + boff[i], &Bs[0][(4 * wv + i) * 512]);
    gl16(gAb + 64 + aoff, &As[1][wv * 512]);
    #pragma unroll
    for (int i = 0; i < 4; i++) gl16(gb + 64 + boff[i], &Bs[1][(4 * wv + i) * 512]);
  }
  asm volatile("s_waitcnt vmcnt(5)" ::: "memory");   // own stage-0 landed
  __builtin_amdgcn_s_barrier();

  const int rc = ((quad ^ ((nl >> 1) & 3)) << 3);    // read-side swizzled chunk
  const int aro = nl * 32 + rc;
  const int bro = (wv * 64 + nl) * 32 + rc;

  f32x4 acc[4][4] = {};
  int cb = 0, sb = 2;
  #pragma unroll 1
  for (int s = 0; s < 25; s++) {
    // reads (compiler-scheduled vs MFMAs below) + stage(s+2)
    const unsigned short* Ab = &As[cb][aro];
    const unsigned short* Bb = &Bs[cb][bro];
    bf16x8 af[4], bfr[4];
    #pragma unroll
    for (int mt = 0; mt < 4; mt++)
      af[mt] = *(const bf16x8*)(Ab + mt * 512);
    #pragma unroll
    for (int nt = 0; nt < 4; nt++)
      bfr[nt] = *(const bf16x8*)(Bb + nt * 512);
    {
      const int kn = s + 2;
      int pn = kn >> 1; if (pn > 12) pn = 12;    // clamp keeps vmcnt uniform
      int off = sOff[pn] + ((kn & 1) << 6);
      const char* ga = gAb + kn * 64;
      const char* gb = z1b + off;
      gl16(ga + aoff, &As[sb][wv * 512]);
      #pragma unroll
      for (int i = 0; i < 4; i++) gl16(gb + boff[i], &Bs[sb][(4 * wv + i) * 512]);
    }
    __builtin_amdgcn_s_setprio(1);
    #pragma unroll
    for (int mt = 0; mt < 4; mt++)
      #pragma unroll
      for (int nt = 0; nt < 4; nt++)
        acc[mt][nt] = MFMA(af[mt], bfr[nt], acc[mt][nt], 0, 0, 0);
    __builtin_amdgcn_s_setprio(0);
    asm volatile("s_waitcnt vmcnt(5)" ::: "memory");   // stage(s+1) landed (own)
    __builtin_amdgcn_s_barrier();                      // orders buffer reuse
    cb = (cb == 2) ? 0 : cb + 1;
    sb = (sb == 2) ? 0 : sb + 1;
  }
  // peeled last step (s=25, cb=1): Bst(25) certified at s=24's vmcnt/b2
  {
    const unsigned short* Ab = &As[1][aro];
    const unsigned short* Bb = &Bs[1][bro];
    bf16x8 af[4], bfr[4];
    #pragma unroll
    for (int mt = 0; mt < 4; mt++)
      af[mt] = *(const bf16x8*)(Ab + mt * 512);
    #pragma unroll
    for (int nt = 0; nt < 4; nt++)
      bfr[nt] = *(const bf16x8*)(Bb + nt * 512);
    #pragma unroll
    for (int mt = 0; mt < 4; mt++)
      #pragma unroll
      for (int nt = 0; nt < 4; nt++)
        acc[mt][nt] = MFMA(af[mt], bfr[nt], acc[mt][nt], 0, 0, 0);
  }

  // epilogue: act2 -> z2T[r][b][o]
  #pragma unroll
  for (int mt = 0; mt < 4; mt++) {
    int ob = mt * 16 + quad * 4;
    f32x4 av = *(const f32x4*)(params + 256 + ob);
    f32x4 bv = *(const f32x4*)(params + 320 + ob);
    #pragma unroll
    for (int nt = 0; nt < 4; nt++) {
      int col = b0 + wv * 64 + nt * 16 + nl;
      f32x4 a = acc[mt][nt];
      us4 w;
      w.x = f2bf(fmaxf(fmaf(a[0], av[0], bv[0]), 0.f));
      w.y = f2bf(fmaxf(fmaf(a[1], av[1], bv[1]), 0.f));
      w.z = f2bf(fmaxf(fmaf(a[2], av[2], bv[2]), 0.f));
      w.w = f2bf(fmaxf(fmaf(a[3], av[3], bv[3]), 0.f));
      *(us4*)(z2T + (r * 2048 + col) * 64 + ob) = w;
    }
  }
}

// ---- gemm2 (R14): block = (btile=256 batches, r): C[128 x 256], 4 waves
//      (2mh x 2nh), wave tile 64 x 128 = 4m x 8n. BK=32, 52 K-steps,
//      triple-buffered 74 KB. Single-barrier step, counted vmcnt(6).
__global__ __launch_bounds__(256, 2) void gemm2(const unsigned short* __restrict__ W23t,
                                                const unsigned short* __restrict__ z2T,
                                                const unsigned short* __restrict__ z3T,
                                                const int* __restrict__ nei,
                                                const float* __restrict__ params,
                                                unsigned short* __restrict__ outT) {
  __shared__ unsigned short As[3][4096];     // 128 rows x 32 shorts per buf (8 KB)
  __shared__ unsigned short Bs[3][8192];     // 256 rows x 32 shorts per buf (16 KB)
  __shared__ int sOff[26];                   // per-plane byte offsets from z2T

  const int bid = blockIdx.x;
  const int r = bid >> 3, btile = bid & 7;   // bid%8 = btile -> one btile per XCD
  const int b0 = btile << 8;
  const int t = threadIdx.x, wv = t >> 6, lane = t & 63;
  const int quad = lane >> 4, nl = lane & 15;
  const int mh = wv >> 1, nh = wv & 1;

  if (t < 26) {
    int idx = t < 13 ? t : t - 13;
    int p = nei[r * 13 + idx];
    sOff[t] = p * (PLANE * 2) + (t < 13 ? 0 : ZTOT * 2);
  }

  // staging geometry: slab = 16 rows x 64 B = 1 KB = one gl16 per wave.
  const int lr = lane >> 2, lj = lane & 3;
  const int sj = ((lj ^ ((lr >> 1) & 3)) << 4);   // byte offset in source row
  int aoff[2];
  #pragma unroll
  for (int i = 0; i < 2; i++) aoff[i] = (16 * (2 * wv + i) + lr) * 3328 + sj;
  int boff[4];
  #pragma unroll
  for (int i = 0; i < 4; i++) boff[i] = (b0 + 16 * (4 * wv + i) + lr) * 128 + sj;

  const char* gAb = (const char*)W23t;
  const char* z2b = (const char*)z2T;

  __syncthreads();                           // sOff visible

  // prologue: stage kn=0 -> buf0, kn=1 -> buf1 (plane 0, halves 0/1)
  {
    const char* gb = z2b + sOff[0];
    #pragma unroll
    for (int i = 0; i < 2; i++) gl16(gAb + aoff[i], &As[0][(2 * wv + i) * 512]);
    #pragma unroll
    for (int i = 0; i < 4; i++) gl16(gb + boff[i], &Bs[0][(4 * wv + i) * 512]);
    #pragma unroll
    for (int i = 0; i < 2; i++) gl16(gAb + 64 + aoff[i], &As[1][(2 * wv + i) * 512]);
    #pragma unroll
    for (int i = 0; i < 4; i++) gl16(gb + 64 + boff[i], &Bs[1][(4 * wv + i) * 512]);
  }
  asm volatile("s_waitcnt vmcnt(6)" ::: "memory");   // own stage-0 landed
  __builtin_amdgcn_s_barrier();                      // everyone's stage-0 landed

  const int rc = ((quad ^ ((nl >> 1) & 3)) << 3);  // read-side swizzled chunk (shorts)
  const int aro = (mh * 64 + nl) * 32 + rc;
  const int bro = (nh * 128 + nl) * 32 + rc;

  f32x4 acc[4][8] = {};
  int cb = 0, sb = 2;                        // compute buf = s%3, stage buf = (s+2)%3
  #pragma unroll 1
  for (int s = 0; s < 51; s++) {
    // reads (compiler-scheduled vs MFMAs below) + stage(s+2)
    const unsigned short* Ab = &As[cb][aro];
    const unsigned short* Bb = &Bs[cb][bro];
    bf16x8 af[4], bfr[8];
    #pragma unroll
    for (int mt = 0; mt < 4; mt++)
      af[mt] = *(const bf16x8*)(Ab + mt * 512);
    #pragma unroll
    for (int nt = 0; nt < 8; nt++)
      bfr[nt] = *(const bf16x8*)(Bb + nt * 512);
    {
      const int kn = s + 2;
      int pn = kn >> 1; if (pn > 25) pn = 25;    // clamp keeps vmcnt uniform
      int off = sOff[pn] + ((kn & 1) << 6);
      const char* ga = gAb + kn * 64;
      const char* gb = z2b + off;
      #pragma unroll
      for (int i = 0; i < 2; i++) gl16(ga + aoff[i], &As[sb][(2 * wv + i) * 512]);
      #pragma unroll
      for (int i = 0; i < 4; i++) gl16(gb + boff[i], &Bs[sb][(4 * wv + i) * 512]);
    }
    __builtin_amdgcn_s_setprio(1);
    #pragma unroll
    for (int mt = 0; mt < 4; mt++)
      #pragma unroll
      for (int nt = 0; nt < 8; nt++)
        acc[mt][nt] = MFMA(af[mt], bfr[nt], acc[mt][nt], 0, 0, 0);
    __builtin_amdgcn_s_setprio(0);
    asm volatile("s_waitcnt vmcnt(6)" ::: "memory");   // stage(s+1) landed (own)
    __builtin_amdgcn_s_barrier();                      // orders buffer reuse
    cb = (cb == 2) ? 0 : cb + 1;
    sb = (sb == 2) ? 0 : sb + 1;
  }
  // peeled last step (s=51, cb=0): stage(51) certified at s=50's vmcnt/b2
  {
    const unsigned short* Ab = &As[0][aro];
    const unsigned short* Bb = &Bs[0][bro];
    bf16x8 af[4], bfr[8];
    #pragma unroll
    for (int mt = 0; mt < 4; mt++)
      af[mt] = *(const bf16x8*)(Ab + mt * 512);
    #pragma unroll
    for (int nt = 0; nt < 8; nt++)
      bfr[nt] = *(const bf16x8*)(Bb + nt * 512);
    #pragma unroll
    for (int mt = 0; mt < 4; mt++)
      #pragma unroll
      for (int nt = 0; nt < 8; nt++)
        acc[mt][nt] = MFMA(af[mt], bfr[nt], acc[mt][nt], 0, 0, 0);
  }

  // epilogue: + cc -> outT[r][b][o] bf16
  #pragma unroll
  for (int mt = 0; mt < 4; mt++) {
    int ob = mh * 64 + mt * 16 + quad * 4;
    f32x4 cv = *(const f32x4*)(params + 384 + ob);
    #pragma unroll
    for (int nt = 0; nt < 8; nt++) {
      int col = b0 + nh * 128 + nt * 16 + nl;
      f32x4 a = acc[mt][nt];
      us4 w;
      w.x = f2bf(a[0] + cv[0]);
      w.y = f2bf(a[1] + cv[1]);
      w.z = f2bf(a[2] + cv[2]);
      w.w = f2bf(a[3] + cv[3]);
      *(us4*)(outT + (r * 2048 + col) * 128 + ob) = w;
    }
  }
}

// ---- transpose-out: outT[r][b][o] bf16 -> out[b][o][r] f32
//      phase 2: float4 stores (60%4==0 -> 4 consecutive i share one o);
//      LDS reads stride 129 words = conflict-free.
__global__ __launch_bounds__(256) void t_out(const unsigned short* __restrict__ outT,
                                             float* __restrict__ out) {
  __shared__ float ot[60 * 129];
  const int b = blockIdx.x, t = threadIdx.x;
  for (int i = t; i < 1920; i += 256) {
    int r = i >> 5, og = (i & 31) << 2;
    us4 v = *(const us4*)(outT + (r * 2048 + b) * 128 + og);
    ot[r * 129 + og + 0] = bf2f(v.x);
    ot[r * 129 + og + 1] = bf2f(v.y);
    ot[r * 129 + og + 2] = bf2f(v.z);
    ot[r * 129 + og + 3] = bf2f(v.w);
  }
  __syncthreads();
  float* dst = out + b * 7680;
  for (int i4 = t * 4; i4 < 7680; i4 += 1024) {
    int o = i4 / 60, r0 = i4 - o * 60;       // r0 in {0,4,...,56}: never crosses o
    float4 v;
    v.x = ot[(r0 + 0) * 129 + o];
    v.y = ot[(r0 + 1) * 129 + o];
    v.z = ot[(r0 + 2) * 129 + o];
    v.w = ot[(r0 + 3) * 129 + o];
    *(float4*)(dst + i4) = v;
  }
}

extern "C" void kernel_launch(void* const* d_in, const int* in_sizes, int n_in,
                              void* d_out, int out_size, void* d_ws, size_t ws_size,
                              hipStream_t stream) {
  const float* x   = (const float*)d_in[0];
  const int*   nei = (const int*)d_in[1];
  const float* g1  = (const float*)d_in[2];
  const float* be1 = (const float*)d_in[3];
  const float* mu1 = (const float*)d_in[4];
  const float* va1 = (const float*)d_in[5];
  const float* W1  = (const float*)d_in[6];
  const float* c1  = (const float*)d_in[7];
  const float* g2  = (const float*)d_in[8];
  const float* be2 = (const float*)d_in[9];
  const float* mu2 = (const float*)d_in[10];
  const float* va2 = (const float*)d_in[11];
  const float* W2  = (const float*)d_in[12];
  const float* c2  = (const float*)d_in[13];
  const float* g3  = (const float*)d_in[14];
  const float* be3 = (const float*)d_in[15];
  const float* mu3 = (const float*)d_in[16];
  const float* va3 = (const float*)d_in[17];
  const float* W3  = (const float*)d_in[18];
  const float* c3  = (const float*)d_in[19];

  // ws layout (63.5 MB): W1t | W23t | params | z2T | z3T | big(z1T ∪ outT)
  unsigned short* W1t  = (unsigned short*)d_ws;
  unsigned short* W23t = W1t + 53248;
  float*          prm  = (float*)(W23t + 212992);
  unsigned short* z2T  = (unsigned short*)(prm + 512);
  unsigned short* z3T  = z2T + ZTOT;
  unsigned short* big  = z3T + ZTOT;       // z1T (read in gemm1) aliases outT (written in gemm2)
  unsigned short* z1T  = big;
  unsigned short* outT = big;

  t_in<<<2048, 256, 0, stream>>>(x, W1, W2, W3,
                                 g1, be1, mu1, va1, c1,
                                 g2, be2, mu2, va2, c2,
                                 g3, be3, mu3, va3, c3,
                                 W1t, W23t, prm, z1T, z3T);
  gemm1<<<480, 256, 0, stream>>>(W1t, z1T, nei, prm, z2T);
  gemm2<<<480, 256, 0, stream>>>(W23t, z2T, z3T, nei, prm, outT);
  t_out<<<2048, 256, 0, stream>>>(outT, (float*)d_out);
}